// Round 14
// baseline (2073.925 us; speedup 1.0000x reference)
//
#include <hip/hip_runtime.h>
#include <stdint.h>

// BinaryAttention on MI355X (gfx950).  B=64, N=197, C=768, H=12, d=64.
//
// ROUND 25 — ATTENTION OCCUPANCY (R24 post-mortem: barrier-free rewrite was
// neutral-to-worse; attn is LATENCY-bound at 3 blocks/CU / 12 waves/CU, not
// barrier-bound). This round, attn only:
//   * grid (768, 4): n-range split across 4 blocks (50/50/50/47 n's each).
//   * LDS diet 34.3 -> 18.8 KB: V kept as int8 (ds_read_i8, 64 consecutive
//     bytes = 4 lanes/dword -> same-word broadcast, conflict-free);
//     rel_table staged as f32 (f32->f64 cvt at use is EXACT).
//   => blocks/CU 3 -> 8 (wave-capped), 32 waves/CU vs 12.
// Per-n math instruction-identical to R24 (same ops, order, values) ->
// absmax unchanged, deterministic. qkv_mf/proj_mf/probe/fallbacks verbatim.

#define NT 197
#define HH 12
#define CD 768
#define NB 64
#define MROWS (NB * NT)   // 12608
#define NBH (NB * HH)     // 768
#define RB 32             // rows per block (scalar GEMM)
#define YB (MROWS / RB)   // 394

typedef double f64x4 __attribute__((ext_vector_type(4)));

// ---- flag-selected flat indexers (flag: 0 = C-order, 1 = F-order) ----
__device__ __forceinline__ size_t idxX(int f, int b, int n, int c) {
  return f ? ((size_t)b + 64u * (size_t)n + 12608u * (size_t)c)
           : ((size_t)(b * NT + n) * CD + c);
}
__device__ __forceinline__ size_t idxRT(int f, int i, int h) {  // rel_table [732,12]
  return f ? ((size_t)i + 732u * (size_t)h) : ((size_t)i * HH + h);
}
__device__ __forceinline__ size_t idxRI(int f, int n, int m) {  // rel_index [197,197]
  return f ? ((size_t)n + 197u * (size_t)m) : ((size_t)n * NT + m);
}

// ---- orientation probe + MFMA D-layout discovery ----
__global__ __launch_bounds__(64) void probe_orient(const int* __restrict__ ri,
                                                   int* __restrict__ flag) {
  const int lane = threadIdx.x;   // 0..63
  const int p = lane & 15, q = lane >> 4;
  // exact-integer asymmetric test: A[m][k]=m*4+k+1, B[k][n]=(k+1)*100+n+1
  const double av = (double)(p * 4 + q + 1);          // A[m=p][k=q]
  const double bv = (double)((q + 1) * 100 + p + 1);  // B[k=q][n=p]
  f64x4 c0 = {0.0, 0.0, 0.0, 0.0};
  f64x4 d = __builtin_amdgcn_mfma_f64_16x16x4f64(av, bv, c0, 0, 0, 0);
  int best = 0;
  #pragma unroll
  for (int cand = 0; cand < 4; cand++) {
    bool ok = true;
    #pragma unroll
    for (int r = 0; r < 4; r++) {
      const int g = (cand & 1) ? (q + 4 * r) : (4 * q + r);
      const int m = (cand & 2) ? p : g;
      const int n = (cand & 2) ? g : p;
      double ref = 0.0;
      #pragma unroll
      for (int k = 0; k < 4; k++)
        ref += (double)((m * 4 + k + 1) * ((k + 1) * 100 + n + 1));
      ok = ok && (d[r] == ref);
    }
    if (__ballot(ok) == 0xFFFFFFFFFFFFFFFFull && best == 0) best = cand + 1;
  }
  if (lane == 0) {
    const int aa = ri[1], bb = ri[197];
    flag[0] = (aa == 730 && bb == 729) ? 1 : 0;
    flag[1] = best;   // 0 = no candidate matched -> scalar fallback
  }
}

// ---------- 1a) qkv GEMM, SCALAR fallback (verbatim R17, verified) ----------
// grid (9, 394), block 256. Runs only if flag[1]==0.
__global__ __launch_bounds__(256, 3) void qkv_g(
    const float* __restrict__ x, const float* __restrict__ w,
    uint64_t* __restrict__ qbits, uint64_t* __restrict__ kbits,
    int8_t* __restrict__ vq8, double* __restrict__ qpart,
    double* __restrict__ kpart, const int* __restrict__ flag) {
  __shared__ float wsm[256][34];
  __shared__ double xsm[RB][32];

  if (flag[1] != 0) return;
  const int f = flag[0];
  const int t = threadIdx.x;
  const int wv = t >> 6, lane = t & 63;
  const int cBase = blockIdx.x * 256;
  const int row0 = blockIdx.y * RB;

  double acc[4][8];
  #pragma unroll
  for (int j = 0; j < 4; j++)
    #pragma unroll
    for (int i = 0; i < 8; i++) acc[j][i] = 0.0;

  if (f == 0) {
    for (int k0 = 0; k0 < CD; k0 += 32) {
      #pragma unroll
      for (int j = 0; j < 8; j++) {
        const int flat = t + 256 * j;
        const int r = flat >> 3, kq = flat & 7;
        const float4 v4 = *reinterpret_cast<const float4*>(
            w + (size_t)(cBase + r) * CD + k0 + kq * 4);
        wsm[r][kq * 4 + 0] = v4.x; wsm[r][kq * 4 + 1] = v4.y;
        wsm[r][kq * 4 + 2] = v4.z; wsm[r][kq * 4 + 3] = v4.w;
      }
      #pragma unroll
      for (int j = 0; j < 4; j++) {
        const int flat = t + 256 * j;
        const int r = flat >> 5, kk = flat & 31;
        xsm[r][kk] = (double)x[(size_t)(row0 + r) * CD + k0 + kk];
      }
      __syncthreads();
      for (int kk = 0; kk < 32; kk += 2) {
        double2 xv[8];
        #pragma unroll
        for (int i = 0; i < 8; i++)
          xv[i] = *reinterpret_cast<const double2*>(&xsm[wv * 8 + i][kk]);
        double w0[4], w1[4];
        #pragma unroll
        for (int j = 0; j < 4; j++) {
          const float2 wf = *reinterpret_cast<const float2*>(&wsm[lane + 64 * j][kk]);
          w0[j] = (double)wf.x; w1[j] = (double)wf.y;
        }
        #pragma unroll
        for (int j = 0; j < 4; j++)
          #pragma unroll
          for (int i = 0; i < 8; i++) {
            acc[j][i] += xv[i].x * w0[j];
            acc[j][i] += xv[i].y * w1[j];
          }
      }
      __syncthreads();
    }
  } else {
    for (int k = 0; k < CD; k++) {
      double w0[4];
      #pragma unroll
      for (int j = 0; j < 4; j++)
        w0[j] = (double)w[(size_t)(cBase + lane + 64 * j) + 2304u * (size_t)k];
      #pragma unroll
      for (int i = 0; i < 8; i++) {
        const int row = row0 + wv * 8 + i, b = row / NT, n = row - b * NT;
        const double xv = (double)x[(size_t)b + 64u * (size_t)n + 12608u * (size_t)k];
        #pragma unroll
        for (int j = 0; j < 4; j++) acc[j][i] += xv * w0[j];
      }
    }
  }

  const int kind = cBase / CD;
  const int hBase = (cBase - kind * CD) >> 6;
  #pragma unroll
  for (int j = 0; j < 4; j++) {
    const int h = hBase + j;
    #pragma unroll
    for (int i = 0; i < 8; i++) {
      const int row = row0 + wv * 8 + i, b = row / NT, n = row - b * NT;
      const int bh = b * HH + h;
      const double a = acc[j][i];
      if (kind == 2) {
        const double sV = 2.0 / 127.0;
        double vc = fmin(fmax(a, -2.0), 2.0);
        double vq = rint(vc / sV);
        vq = fmin(fmax(vq, -127.0), 127.0);
        vq8[(size_t)(bh * NT + n) * 64 + lane] = (int8_t)(int)vq;
      } else {
        const uint64_t msk = __ballot(a < 0.0);
        double s = fabs(a);
        #pragma unroll
        for (int off = 1; off < 64; off <<= 1) s += __shfl_xor(s, off);
        if (lane == 0) {
          if (kind == 0) { qbits[(size_t)bh * NT + n] = msk; qpart[(size_t)bh * NT + n] = s; }
          else           { kbits[(size_t)bh * NT + n] = msk; kpart[(size_t)bh * NT + n] = s; }
        }
      }
    }
  }
}

// ---------- 1b) qkv GEMM via f64 MFMA (runs only if flag[1]>=1) ----------
// grid (36, 197), block 256 = 4 waves, 64x64 tile.
union SmemQ {
  struct { double xs[64][33]; double ws[64][33]; } t;   // K-loop tiles
  double d[64][65];                                     // D round-trip
};
__global__ __launch_bounds__(256) void qkv_mf(
    const float* __restrict__ x, const float* __restrict__ w,
    uint64_t* __restrict__ qbits, uint64_t* __restrict__ kbits,
    int8_t* __restrict__ vq8, double* __restrict__ qpart,
    double* __restrict__ kpart, const int* __restrict__ flag) {
  __shared__ SmemQ sm;

  if (flag[1] == 0) return;
  const int dmap = flag[1] - 1;
  const int f = flag[0];
  const int t = threadIdx.x;
  const int wv = t >> 6, lane = t & 63;
  const int p = lane & 15, q = lane >> 4;
  const int cBase = blockIdx.x * 64;
  const int row0 = blockIdx.y * 64;
  const int kind = cBase / CD;
  const int h = (cBase - kind * CD) >> 6;

  f64x4 acc[4];
  #pragma unroll
  for (int j = 0; j < 4; j++) acc[j] = (f64x4){0.0, 0.0, 0.0, 0.0};

  for (int k0 = 0; k0 < CD; k0 += 32) {
    if (f == 0) {
      #pragma unroll
      for (int jj = 0; jj < 2; jj++) {
        const int idx = t + 256 * jj;
        const int r = idx >> 3, kq = idx & 7;
        const float4 v4 = *reinterpret_cast<const float4*>(
            x + (size_t)(row0 + r) * CD + k0 + kq * 4);
        sm.t.xs[r][kq * 4 + 0] = (double)v4.x; sm.t.xs[r][kq * 4 + 1] = (double)v4.y;
        sm.t.xs[r][kq * 4 + 2] = (double)v4.z; sm.t.xs[r][kq * 4 + 3] = (double)v4.w;
      }
      #pragma unroll
      for (int jj = 0; jj < 2; jj++) {
        const int idx = t + 256 * jj;
        const int r = idx >> 3, kq = idx & 7;
        const float4 v4 = *reinterpret_cast<const float4*>(
            w + (size_t)(cBase + r) * CD + k0 + kq * 4);
        sm.t.ws[r][kq * 4 + 0] = (double)v4.x; sm.t.ws[r][kq * 4 + 1] = (double)v4.y;
        sm.t.ws[r][kq * 4 + 2] = (double)v4.z; sm.t.ws[r][kq * 4 + 3] = (double)v4.w;
      }
    } else {
      for (int idx = t; idx < 2048; idx += 256) {
        const int r = idx >> 5, kk = idx & 31;
        const int row = row0 + r, b = row / NT, n = row - b * NT;
        sm.t.xs[r][kk] = (double)x[(size_t)b + 64u * (size_t)n + 12608u * (size_t)(k0 + kk)];
        sm.t.ws[r][kk] = (double)w[(size_t)(cBase + r) + 2304u * (size_t)(k0 + kk)];
      }
    }
    __syncthreads();
    #pragma unroll
    for (int ks = 0; ks < 8; ks++) {
      const double a = sm.t.xs[wv * 16 + p][ks * 4 + q];
      #pragma unroll
      for (int j = 0; j < 4; j++) {
        const double bb = sm.t.ws[j * 16 + p][ks * 4 + q];
        acc[j] = __builtin_amdgcn_mfma_f64_16x16x4f64(a, bb, acc[j], 0, 0, 0);
      }
    }
    __syncthreads();
  }

  // D -> LDS via the DISCOVERED map, then R17-structure epilogue.
  #pragma unroll
  for (int j = 0; j < 4; j++)
    #pragma unroll
    for (int r = 0; r < 4; r++) {
      const int g = (dmap & 1) ? (q + 4 * r) : (4 * q + r);
      const int rr = (dmap & 2) ? p : g;
      const int cc = (dmap & 2) ? g : p;
      sm.d[wv * 16 + rr][j * 16 + cc] = acc[j][r];
    }
  __syncthreads();

  if (kind == 2) {
    const double sV = 2.0 / 127.0;
    for (int i = 0; i < 16; i++) {
      const int row = row0 + wv * 16 + i;
      const int b = row / NT, n = row - b * NT, bh = b * HH + h;
      const double a = sm.d[wv * 16 + i][lane];
      double vc = fmin(fmax(a, -2.0), 2.0);
      double vq = rint(vc / sV);
      vq = fmin(fmax(vq, -127.0), 127.0);
      vq8[(size_t)(bh * NT + n) * 64 + lane] = (int8_t)(int)vq;
    }
  } else {
    for (int i = 0; i < 16; i++) {
      const int row = row0 + wv * 16 + i;
      const int b = row / NT, n = row - b * NT, bh = b * HH + h;
      const double a = sm.d[wv * 16 + i][lane];
      const uint64_t msk = __ballot(a < 0.0);
      double s = fabs(a);
      #pragma unroll
      for (int off = 1; off < 64; off <<= 1) s += __shfl_xor(s, off);
      if (lane == 0) {
        if (kind == 0) { qbits[(size_t)bh * NT + n] = msk; qpart[(size_t)bh * NT + n] = s; }
        else           { kbits[(size_t)bh * NT + n] = msk; kpart[(size_t)bh * NT + n] = s; }
      }
    }
  }
}

// ---------- 1c) deterministic fixed-order reduction of row partials ----------
__global__ __launch_bounds__(256) void reduce_s(
    const double* __restrict__ qpart, const double* __restrict__ kpart,
    double* __restrict__ sqa, double* __restrict__ ska) {
  __shared__ double sh[256];
  const int bh = blockIdx.x, t = threadIdx.x;
  sh[t] = (t < NT) ? qpart[(size_t)bh * NT + t] : 0.0;
  __syncthreads();
  for (int s = 128; s > 0; s >>= 1) { if (t < s) sh[t] += sh[t + s]; __syncthreads(); }
  if (t == 0) sqa[bh] = sh[0];
  __syncthreads();
  sh[t] = (t < NT) ? kpart[(size_t)bh * NT + t] : 0.0;
  __syncthreads();
  for (int s = 128; s > 0; s >>= 1) { if (t < s) sh[t] += sh[t + s]; __syncthreads(); }
  if (t == 0) ska[bh] = sh[0];
}

// ---------- 2) attention: barrier-free, n-range split 4 ways ----------
// grid (768, 4), block 256 = 4 waves. Per-n math identical to R24; LDS
// 18.8 KB (V int8 broadcast-read, rel_table f32) -> 8 blocks/CU, 32 waves.
__global__ __launch_bounds__(256) void attn_f64(
    const uint64_t* __restrict__ qbits, const uint64_t* __restrict__ kbits,
    const int8_t* __restrict__ vq8, const double* __restrict__ sqa,
    const double* __restrict__ ska, const float* __restrict__ rel_table,
    const int* __restrict__ rel_index, int* __restrict__ attn_acc,
    const int* __restrict__ flag) {
  __shared__ uint64_t qsh[NT];
  __shared__ uint64_t ksh[NT];
  __shared__ int8_t vsh8[NT * 64];   // 12.6 KB, raw int8 (broadcast reads)
  __shared__ float rtabf[732];       // 2.9 KB f32 (cvt at use is exact)

  const int f = flag[0];
  const int bh = blockIdx.x;
  const int qtr = blockIdx.y;        // 0..3
  const int n0 = qtr * 50;
  const int n1 = (qtr == 3) ? NT : n0 + 50;
  const int b = bh / HH, h = bh - b * HH;
  const int t = threadIdx.x;
  const int wv = t >> 6, lane = t & 63;

  const double s_q = sqa[bh] / (double)(NT * 64);
  const double s_k = ska[bh] / (double)(NT * 64);
  const double coef = s_q * s_k * 0.125;

  if (t < NT) {
    qsh[t] = qbits[(size_t)bh * NT + t];
    ksh[t] = kbits[(size_t)bh * NT + t];
  }
  for (int idx = t; idx < 732; idx += 256)
    rtabf[idx] = rel_table[idxRT(f, idx, h)];
  {
    const int4* vsrc = (const int4*)(vq8 + (size_t)bh * NT * 64);
    int4* vdst = (int4*)vsh8;
    for (int idx = t; idx < NT * 4; idx += 256)   // 788 int4 words
      vdst[idx] = vsrc[idx];
  }
  __syncthreads();   // the ONLY barrier

  int* aout = attn_acc + (size_t)(b * NT) * CD + h * 64;   // + n*CD + dd

  for (int n = n0 + wv; n < n1; n += 4) {
    const uint64_t qb = qsh[n];
    // logits for m = lane + 64*i (i=3 valid only for lane<5)
    double lt[4];
    #pragma unroll
    for (int i = 0; i < 4; i++) {
      const int m = lane + 64 * i;
      if (m < NT) {
        const int dot = 64 - 2 * (int)__popcll(qb ^ ksh[m]);
        lt[i] = coef * (double)dot + (double)rtabf[rel_index[idxRI(f, n, m)]];
      } else {
        lt[i] = -1e300;
      }
    }
    // wave max: exact (order-independent)
    double mx = fmax(fmax(lt[0], lt[1]), fmax(lt[2], lt[3]));
    #pragma unroll
    for (int off = 1; off < 64; off <<= 1) mx = fmax(mx, __shfl_xor(mx, off));
    // exp + FIXED-order sum (in-lane pairs, then butterfly: deterministic)
    double et[4];
    #pragma unroll
    for (int i = 0; i < 4; i++)
      et[i] = (lane + 64 * i < NT) ? exp(lt[i] - mx) : 0.0;
    double sl = (et[0] + et[1]) + (et[2] + et[3]);
    #pragma unroll
    for (int off = 1; off < 64; off <<= 1) sl += __shfl_xor(sl, off);
    const double sum = sl;
    // P in registers (int), invalid slots = 0
    const double sP = 1.0 / 255.0;
    int Pint[4];
    #pragma unroll
    for (int i = 0; i < 4; i++) {
      if (lane + 64 * i < NT) {
        double P = rint((et[i] / sum) / sP);
        P = fmin(fmax(P, 0.0), 255.0);
        Pint[i] = (int)P;
      } else {
        Pint[i] = 0;
      }
    }
    // PV: ascending m, single int accumulator (exact, deterministic).
    // P broadcast via __shfl; V int8 from LDS (64 consecutive bytes ->
    // 4 lanes share a dword -> same-word broadcast, conflict-free).
    int acc = 0;
    #pragma unroll
    for (int i = 0; i < 3; i++) {
      for (int mm = 0; mm < 64; mm++) {
        const int Pm = __shfl(Pint[i], mm);
        acc += Pm * (int)vsh8[(i * 64 + mm) * 64 + lane];
      }
    }
    for (int mm = 0; mm < 5; mm++) {
      const int Pm = __shfl(Pint[3], mm);
      acc += Pm * (int)vsh8[(192 + mm) * 64 + lane];
    }
    aout[(size_t)n * CD + lane] = acc;
  }
}

// ---------- 3a) proj GEMM, SCALAR fallback (verbatim R17) ----------
// grid (3, 394). Runs only if flag[1]==0.
__global__ __launch_bounds__(256, 3) void proj_g(
    const int* __restrict__ attn_acc, const float* __restrict__ w,
    const float* __restrict__ bias, float* __restrict__ out,
    const int* __restrict__ flag) {
  __shared__ float wsm[256][34];
  __shared__ double xsm[RB][32];

  if (flag[1] != 0) return;
  const int f = flag[0];
  const int t = threadIdx.x;
  const int wv = t >> 6, lane = t & 63;
  const int cBase = blockIdx.x * 256;
  const int row0 = blockIdx.y * RB;

  double acc[4][8];
  #pragma unroll
  for (int j = 0; j < 4; j++)
    #pragma unroll
    for (int i = 0; i < 8; i++) acc[j][i] = 0.0;

  if (f == 0) {
    for (int k0 = 0; k0 < CD; k0 += 32) {
      #pragma unroll
      for (int j = 0; j < 8; j++) {
        const int flat = t + 256 * j;
        const int r = flat >> 3, kq = flat & 7;
        const float4 v4 = *reinterpret_cast<const float4*>(
            w + (size_t)(cBase + r) * CD + k0 + kq * 4);
        wsm[r][kq * 4 + 0] = v4.x; wsm[r][kq * 4 + 1] = v4.y;
        wsm[r][kq * 4 + 2] = v4.z; wsm[r][kq * 4 + 3] = v4.w;
      }
      #pragma unroll
      for (int j = 0; j < 4; j++) {
        const int flat = t + 256 * j;
        const int r = flat >> 5, kk = flat & 31;
        xsm[r][kk] = (double)attn_acc[(size_t)(row0 + r) * CD + k0 + kk];
      }
      __syncthreads();
      for (int kk = 0; kk < 32; kk += 2) {
        double2 xv[8];
        #pragma unroll
        for (int i = 0; i < 8; i++)
          xv[i] = *reinterpret_cast<const double2*>(&xsm[wv * 8 + i][kk]);
        double w0[4], w1[4];
        #pragma unroll
        for (int j = 0; j < 4; j++) {
          const float2 wf = *reinterpret_cast<const float2*>(&wsm[lane + 64 * j][kk]);
          w0[j] = (double)wf.x; w1[j] = (double)wf.y;
        }
        #pragma unroll
        for (int j = 0; j < 4; j++)
          #pragma unroll
          for (int i = 0; i < 8; i++) {
            acc[j][i] += xv[i].x * w0[j];
            acc[j][i] += xv[i].y * w1[j];
          }
      }
      __syncthreads();
    }
  } else {
    for (int k = 0; k < CD; k++) {
      double w0[4];
      #pragma unroll
      for (int j = 0; j < 4; j++)
        w0[j] = (double)w[(size_t)(cBase + lane + 64 * j) + 768u * (size_t)k];
      #pragma unroll
      for (int i = 0; i < 8; i++) {
        const double xv = (double)attn_acc[(size_t)(row0 + wv * 8 + i) * CD + k];
        #pragma unroll
        for (int j = 0; j < 4; j++) acc[j][i] += xv * w0[j];
      }
    }
  }

  const double SCALE = (1.0 / 255.0) * (2.0 / 127.0);
  #pragma unroll
  for (int j = 0; j < 4; j++) {
    const int c = cBase + lane + 64 * j;
    const double bj = (double)bias[c];
    #pragma unroll
    for (int i = 0; i < 8; i++) {
      const int row = row0 + wv * 8 + i, b = row / NT, n = row - b * NT;
      out[idxX(f, b, n, c)] = (float)(acc[j][i] * SCALE + bj);
    }
  }
}

// ---------- 3b) proj GEMM via f64 MFMA (runs only if flag[1]>=1) ----------
// grid (12, 197), block 256 = 4 waves, 64x64 tile.
__global__ __launch_bounds__(256) void proj_mf(
    const int* __restrict__ attn_acc, const float* __restrict__ w,
    const float* __restrict__ bias, float* __restrict__ out,
    const int* __restrict__ flag) {
  __shared__ double xsm[64][33];
  __shared__ double wsm[64][33];

  if (flag[1] == 0) return;
  const int dmap = flag[1] - 1;
  const int f = flag[0];
  const int t = threadIdx.x;
  const int wv = t >> 6, lane = t & 63;
  const int p = lane & 15, q = lane >> 4;
  const int cBase = blockIdx.x * 64;
  const int row0 = blockIdx.y * 64;

  f64x4 acc[4];
  #pragma unroll
  for (int j = 0; j < 4; j++) acc[j] = (f64x4){0.0, 0.0, 0.0, 0.0};

  for (int k0 = 0; k0 < CD; k0 += 32) {
    #pragma unroll
    for (int jj = 0; jj < 2; jj++) {
      const int idx = t + 256 * jj;
      const int r = idx >> 3, kq = idx & 7;
      const int4 v4 = *reinterpret_cast<const int4*>(
          attn_acc + (size_t)(row0 + r) * CD + k0 + kq * 4);
      xsm[r][kq * 4 + 0] = (double)v4.x; xsm[r][kq * 4 + 1] = (double)v4.y;
      xsm[r][kq * 4 + 2] = (double)v4.z; xsm[r][kq * 4 + 3] = (double)v4.w;
    }
    if (f == 0) {
      #pragma unroll
      for (int jj = 0; jj < 2; jj++) {
        const int idx = t + 256 * jj;
        const int r = idx >> 3, kq = idx & 7;
        const float4 v4 = *reinterpret_cast<const float4*>(
            w + (size_t)(cBase + r) * CD + k0 + kq * 4);
        wsm[r][kq * 4 + 0] = (double)v4.x; wsm[r][kq * 4 + 1] = (double)v4.y;
        wsm[r][kq * 4 + 2] = (double)v4.z; wsm[r][kq * 4 + 3] = (double)v4.w;
      }
    } else {
      for (int idx = t; idx < 2048; idx += 256) {
        const int r = idx >> 5, kk = idx & 31;
        wsm[r][kk] = (double)w[(size_t)(cBase + r) + 768u * (size_t)(k0 + kk)];
      }
    }
    __syncthreads();
    #pragma unroll
    for (int ks = 0; ks < 8; ks++) {
      const double a = xsm[wv * 16 + p][ks * 4 + q];
      #pragma unroll
      for (int j = 0; j < 4; j++) {
        const double bb = wsm[j * 16 + p][ks * 4 + q];
        acc[j] = __builtin_amdgcn_mfma_f64_16x16x4f64(a, bb, acc[j], 0, 0, 0);
      }
    }
    __syncthreads();
  }

  const double SCALE = (1.0 / 255.0) * (2.0 / 127.0);
  #pragma unroll
  for (int j = 0; j < 4; j++) {
    #pragma unroll
    for (int r = 0; r < 4; r++) {
      const int g = (dmap & 1) ? (q + 4 * r) : (4 * q + r);
      const int rr = (dmap & 2) ? p : g;
      const int cc = (dmap & 2) ? g : p;
      const int row = row0 + wv * 16 + rr;
      const int b = row / NT, n = row - b * NT;
      const int c = cBase + j * 16 + cc;
      out[idxX(f, b, n, c)] = (float)(acc[j][r] * SCALE + (double)bias[c]);
    }
  }
}

// ---------------- host launch ----------------
extern "C" void kernel_launch(void* const* d_in, const int* in_sizes, int n_in,
                              void* d_out, int out_size, void* d_ws, size_t ws_size,
                              hipStream_t stream) {
  (void)out_size; (void)ws_size;

  const float* x = nullptr;
  const float* qkv_w = nullptr;
  const float* proj_w = nullptr;
  const float* proj_b = nullptr;
  const float* rel_table = nullptr;
  const int* rel_index = nullptr;
  for (int i = 0; i < n_in; i++) {
    switch (in_sizes[i]) {
      case 9682944: x         = (const float*)d_in[i]; break;
      case 1769472: qkv_w     = (const float*)d_in[i]; break;
      case 589824:  proj_w    = (const float*)d_in[i]; break;
      case 768:     proj_b    = (const float*)d_in[i]; break;
      case 8784:    rel_table = (const float*)d_in[i]; break;
      case 38809:   rel_index = (const int*)d_in[i];   break;
      default: break;
    }
  }
  if (!x)         x         = (const float*)d_in[0];
  if (!qkv_w)     qkv_w     = (const float*)d_in[1];
  if (!proj_w)    proj_w    = (const float*)d_in[2];
  if (!proj_b)    proj_b    = (const float*)d_in[3];
  if (!rel_table) rel_table = (const float*)d_in[4];
  if (!rel_index) rel_index = (const int*)d_in[5];
  float* out = (float*)d_out;

  uint8_t* ws = (uint8_t*)d_ws;
  int*      flag     = (int*)(ws + 0);              //         64
  double*   sqa      = (double*)(ws + 64);          //      6,144
  double*   ska      = (double*)(ws + 6208);        //      6,144
  double*   qpart    = (double*)(ws + 12352);       //  1,210,368
  double*   kpart    = (double*)(ws + 1222720);     //  1,210,368
  uint64_t* qbits    = (uint64_t*)(ws + 2433088);   //  1,210,368
  uint64_t* kbits    = (uint64_t*)(ws + 3643456);   //  1,210,368
  int8_t*   vq8      = (int8_t*)(ws + 4853824);     //  9,682,944
  int*      attn_acc = (int*)(ws + 14536768);       // 38,731,776 -> 53,268,544

  probe_orient<<<1, 64, 0, stream>>>(rel_index, flag);
  // both qkv variants launch; exactly one does work (flag[1] guard)
  qkv_g<<<dim3(9, YB), 256, 0, stream>>>(x, qkv_w, qbits, kbits, vq8,
                                         qpart, kpart, flag);
  qkv_mf<<<dim3(36, 197), 256, 0, stream>>>(x, qkv_w, qbits, kbits, vq8,
                                            qpart, kpart, flag);
  reduce_s<<<NBH, 256, 0, stream>>>(qpart, kpart, sqa, ska);
  attn_f64<<<dim3(NBH, 4), 256, 0, stream>>>(qbits, kbits, vq8, sqa, ska,
                                             rel_table, rel_index, attn_acc, flag);
  proj_g<<<dim3(3, YB), 256, 0, stream>>>(attn_acc, proj_w, proj_b, out, flag);
  proj_mf<<<dim3(12, 197), 256, 0, stream>>>(attn_acc, proj_w, proj_b, out, flag);
}

// Round 15
// 1477.845 us; speedup vs baseline: 1.4033x; 1.4033x over previous
//
#include <hip/hip_runtime.h>
#include <stdint.h>

// BinaryAttention on MI355X (gfx950).  B=64, N=197, C=768, H=12, d=64.
//
// ROUND 26 — PV VIA LDS-P + 4 ACCUMULATORS (attn only).
// R25 profile: attn_f64 = 915 us, VGPR=168, Occupancy 11.7%, VALUBusy 19%
// -> VGPR-capped occupancy + serial PV: 197 __shfl (ds_bpermute ~30cy) into
// ONE dependent int-MAC chain, Pint/et/lt live throughout. This round:
//   * P written to psh[wv][0..196] (int LDS strip, same-wave, no barrier),
//     PV reads P via broadcast ds_read (conflict-free) — no shfl, short
//     register lifetimes.
//   * 4 independent int accumulators over m<196 + tail m=196 (exact,
//     associative -> deterministic, bit-identical output).
// All vsh8 indices < NT*64 (in bounds). qkv_mf/proj_mf (discovered D-map),
// probe, fallbacks, reduce_s, grid (768,4): verbatim R25 (passing).

#define NT 197
#define HH 12
#define CD 768
#define NB 64
#define MROWS (NB * NT)   // 12608
#define NBH (NB * HH)     // 768
#define RB 32             // rows per block (scalar GEMM)
#define YB (MROWS / RB)   // 394

typedef double f64x4 __attribute__((ext_vector_type(4)));

// ---- flag-selected flat indexers (flag: 0 = C-order, 1 = F-order) ----
__device__ __forceinline__ size_t idxX(int f, int b, int n, int c) {
  return f ? ((size_t)b + 64u * (size_t)n + 12608u * (size_t)c)
           : ((size_t)(b * NT + n) * CD + c);
}
__device__ __forceinline__ size_t idxRT(int f, int i, int h) {  // rel_table [732,12]
  return f ? ((size_t)i + 732u * (size_t)h) : ((size_t)i * HH + h);
}
__device__ __forceinline__ size_t idxRI(int f, int n, int m) {  // rel_index [197,197]
  return f ? ((size_t)n + 197u * (size_t)m) : ((size_t)n * NT + m);
}

// ---- orientation probe + MFMA D-layout discovery ----
__global__ __launch_bounds__(64) void probe_orient(const int* __restrict__ ri,
                                                   int* __restrict__ flag) {
  const int lane = threadIdx.x;   // 0..63
  const int p = lane & 15, q = lane >> 4;
  const double av = (double)(p * 4 + q + 1);          // A[m=p][k=q]
  const double bv = (double)((q + 1) * 100 + p + 1);  // B[k=q][n=p]
  f64x4 c0 = {0.0, 0.0, 0.0, 0.0};
  f64x4 d = __builtin_amdgcn_mfma_f64_16x16x4f64(av, bv, c0, 0, 0, 0);
  int best = 0;
  #pragma unroll
  for (int cand = 0; cand < 4; cand++) {
    bool ok = true;
    #pragma unroll
    for (int r = 0; r < 4; r++) {
      const int g = (cand & 1) ? (q + 4 * r) : (4 * q + r);
      const int m = (cand & 2) ? p : g;
      const int n = (cand & 2) ? g : p;
      double ref = 0.0;
      #pragma unroll
      for (int k = 0; k < 4; k++)
        ref += (double)((m * 4 + k + 1) * ((k + 1) * 100 + n + 1));
      ok = ok && (d[r] == ref);
    }
    if (__ballot(ok) == 0xFFFFFFFFFFFFFFFFull && best == 0) best = cand + 1;
  }
  if (lane == 0) {
    const int aa = ri[1], bb = ri[197];
    flag[0] = (aa == 730 && bb == 729) ? 1 : 0;
    flag[1] = best;   // 0 = no candidate matched -> scalar fallback
  }
}

// ---------- 1a) qkv GEMM, SCALAR fallback (verbatim R17, verified) ----------
__global__ __launch_bounds__(256, 3) void qkv_g(
    const float* __restrict__ x, const float* __restrict__ w,
    uint64_t* __restrict__ qbits, uint64_t* __restrict__ kbits,
    int8_t* __restrict__ vq8, double* __restrict__ qpart,
    double* __restrict__ kpart, const int* __restrict__ flag) {
  __shared__ float wsm[256][34];
  __shared__ double xsm[RB][32];

  if (flag[1] != 0) return;
  const int f = flag[0];
  const int t = threadIdx.x;
  const int wv = t >> 6, lane = t & 63;
  const int cBase = blockIdx.x * 256;
  const int row0 = blockIdx.y * RB;

  double acc[4][8];
  #pragma unroll
  for (int j = 0; j < 4; j++)
    #pragma unroll
    for (int i = 0; i < 8; i++) acc[j][i] = 0.0;

  if (f == 0) {
    for (int k0 = 0; k0 < CD; k0 += 32) {
      #pragma unroll
      for (int j = 0; j < 8; j++) {
        const int flat = t + 256 * j;
        const int r = flat >> 3, kq = flat & 7;
        const float4 v4 = *reinterpret_cast<const float4*>(
            w + (size_t)(cBase + r) * CD + k0 + kq * 4);
        wsm[r][kq * 4 + 0] = v4.x; wsm[r][kq * 4 + 1] = v4.y;
        wsm[r][kq * 4 + 2] = v4.z; wsm[r][kq * 4 + 3] = v4.w;
      }
      #pragma unroll
      for (int j = 0; j < 4; j++) {
        const int flat = t + 256 * j;
        const int r = flat >> 5, kk = flat & 31;
        xsm[r][kk] = (double)x[(size_t)(row0 + r) * CD + k0 + kk];
      }
      __syncthreads();
      for (int kk = 0; kk < 32; kk += 2) {
        double2 xv[8];
        #pragma unroll
        for (int i = 0; i < 8; i++)
          xv[i] = *reinterpret_cast<const double2*>(&xsm[wv * 8 + i][kk]);
        double w0[4], w1[4];
        #pragma unroll
        for (int j = 0; j < 4; j++) {
          const float2 wf = *reinterpret_cast<const float2*>(&wsm[lane + 64 * j][kk]);
          w0[j] = (double)wf.x; w1[j] = (double)wf.y;
        }
        #pragma unroll
        for (int j = 0; j < 4; j++)
          #pragma unroll
          for (int i = 0; i < 8; i++) {
            acc[j][i] += xv[i].x * w0[j];
            acc[j][i] += xv[i].y * w1[j];
          }
      }
      __syncthreads();
    }
  } else {
    for (int k = 0; k < CD; k++) {
      double w0[4];
      #pragma unroll
      for (int j = 0; j < 4; j++)
        w0[j] = (double)w[(size_t)(cBase + lane + 64 * j) + 2304u * (size_t)k];
      #pragma unroll
      for (int i = 0; i < 8; i++) {
        const int row = row0 + wv * 8 + i, b = row / NT, n = row - b * NT;
        const double xv = (double)x[(size_t)b + 64u * (size_t)n + 12608u * (size_t)k];
        #pragma unroll
        for (int j = 0; j < 4; j++) acc[j][i] += xv * w0[j];
      }
    }
  }

  const int kind = cBase / CD;
  const int hBase = (cBase - kind * CD) >> 6;
  #pragma unroll
  for (int j = 0; j < 4; j++) {
    const int h = hBase + j;
    #pragma unroll
    for (int i = 0; i < 8; i++) {
      const int row = row0 + wv * 8 + i, b = row / NT, n = row - b * NT;
      const int bh = b * HH + h;
      const double a = acc[j][i];
      if (kind == 2) {
        const double sV = 2.0 / 127.0;
        double vc = fmin(fmax(a, -2.0), 2.0);
        double vq = rint(vc / sV);
        vq = fmin(fmax(vq, -127.0), 127.0);
        vq8[(size_t)(bh * NT + n) * 64 + lane] = (int8_t)(int)vq;
      } else {
        const uint64_t msk = __ballot(a < 0.0);
        double s = fabs(a);
        #pragma unroll
        for (int off = 1; off < 64; off <<= 1) s += __shfl_xor(s, off);
        if (lane == 0) {
          if (kind == 0) { qbits[(size_t)bh * NT + n] = msk; qpart[(size_t)bh * NT + n] = s; }
          else           { kbits[(size_t)bh * NT + n] = msk; kpart[(size_t)bh * NT + n] = s; }
        }
      }
    }
  }
}

// ---------- 1b) qkv GEMM via f64 MFMA (runs only if flag[1]>=1) ----------
union SmemQ {
  struct { double xs[64][33]; double ws[64][33]; } t;   // K-loop tiles
  double d[64][65];                                     // D round-trip
};
__global__ __launch_bounds__(256) void qkv_mf(
    const float* __restrict__ x, const float* __restrict__ w,
    uint64_t* __restrict__ qbits, uint64_t* __restrict__ kbits,
    int8_t* __restrict__ vq8, double* __restrict__ qpart,
    double* __restrict__ kpart, const int* __restrict__ flag) {
  __shared__ SmemQ sm;

  if (flag[1] == 0) return;
  const int dmap = flag[1] - 1;
  const int f = flag[0];
  const int t = threadIdx.x;
  const int wv = t >> 6, lane = t & 63;
  const int p = lane & 15, q = lane >> 4;
  const int cBase = blockIdx.x * 64;
  const int row0 = blockIdx.y * 64;
  const int kind = cBase / CD;
  const int h = (cBase - kind * CD) >> 6;

  f64x4 acc[4];
  #pragma unroll
  for (int j = 0; j < 4; j++) acc[j] = (f64x4){0.0, 0.0, 0.0, 0.0};

  for (int k0 = 0; k0 < CD; k0 += 32) {
    if (f == 0) {
      #pragma unroll
      for (int jj = 0; jj < 2; jj++) {
        const int idx = t + 256 * jj;
        const int r = idx >> 3, kq = idx & 7;
        const float4 v4 = *reinterpret_cast<const float4*>(
            x + (size_t)(row0 + r) * CD + k0 + kq * 4);
        sm.t.xs[r][kq * 4 + 0] = (double)v4.x; sm.t.xs[r][kq * 4 + 1] = (double)v4.y;
        sm.t.xs[r][kq * 4 + 2] = (double)v4.z; sm.t.xs[r][kq * 4 + 3] = (double)v4.w;
      }
      #pragma unroll
      for (int jj = 0; jj < 2; jj++) {
        const int idx = t + 256 * jj;
        const int r = idx >> 3, kq = idx & 7;
        const float4 v4 = *reinterpret_cast<const float4*>(
            w + (size_t)(cBase + r) * CD + k0 + kq * 4);
        sm.t.ws[r][kq * 4 + 0] = (double)v4.x; sm.t.ws[r][kq * 4 + 1] = (double)v4.y;
        sm.t.ws[r][kq * 4 + 2] = (double)v4.z; sm.t.ws[r][kq * 4 + 3] = (double)v4.w;
      }
    } else {
      for (int idx = t; idx < 2048; idx += 256) {
        const int r = idx >> 5, kk = idx & 31;
        const int row = row0 + r, b = row / NT, n = row - b * NT;
        sm.t.xs[r][kk] = (double)x[(size_t)b + 64u * (size_t)n + 12608u * (size_t)(k0 + kk)];
        sm.t.ws[r][kk] = (double)w[(size_t)(cBase + r) + 2304u * (size_t)(k0 + kk)];
      }
    }
    __syncthreads();
    #pragma unroll
    for (int ks = 0; ks < 8; ks++) {
      const double a = sm.t.xs[wv * 16 + p][ks * 4 + q];
      #pragma unroll
      for (int j = 0; j < 4; j++) {
        const double bb = sm.t.ws[j * 16 + p][ks * 4 + q];
        acc[j] = __builtin_amdgcn_mfma_f64_16x16x4f64(a, bb, acc[j], 0, 0, 0);
      }
    }
    __syncthreads();
  }

  #pragma unroll
  for (int j = 0; j < 4; j++)
    #pragma unroll
    for (int r = 0; r < 4; r++) {
      const int g = (dmap & 1) ? (q + 4 * r) : (4 * q + r);
      const int rr = (dmap & 2) ? p : g;
      const int cc = (dmap & 2) ? g : p;
      sm.d[wv * 16 + rr][j * 16 + cc] = acc[j][r];
    }
  __syncthreads();

  if (kind == 2) {
    const double sV = 2.0 / 127.0;
    for (int i = 0; i < 16; i++) {
      const int row = row0 + wv * 16 + i;
      const int b = row / NT, n = row - b * NT, bh = b * HH + h;
      const double a = sm.d[wv * 16 + i][lane];
      double vc = fmin(fmax(a, -2.0), 2.0);
      double vq = rint(vc / sV);
      vq = fmin(fmax(vq, -127.0), 127.0);
      vq8[(size_t)(bh * NT + n) * 64 + lane] = (int8_t)(int)vq;
    }
  } else {
    for (int i = 0; i < 16; i++) {
      const int row = row0 + wv * 16 + i;
      const int b = row / NT, n = row - b * NT, bh = b * HH + h;
      const double a = sm.d[wv * 16 + i][lane];
      const uint64_t msk = __ballot(a < 0.0);
      double s = fabs(a);
      #pragma unroll
      for (int off = 1; off < 64; off <<= 1) s += __shfl_xor(s, off);
      if (lane == 0) {
        if (kind == 0) { qbits[(size_t)bh * NT + n] = msk; qpart[(size_t)bh * NT + n] = s; }
        else           { kbits[(size_t)bh * NT + n] = msk; kpart[(size_t)bh * NT + n] = s; }
      }
    }
  }
}

// ---------- 1c) deterministic fixed-order reduction of row partials ----------
__global__ __launch_bounds__(256) void reduce_s(
    const double* __restrict__ qpart, const double* __restrict__ kpart,
    double* __restrict__ sqa, double* __restrict__ ska) {
  __shared__ double sh[256];
  const int bh = blockIdx.x, t = threadIdx.x;
  sh[t] = (t < NT) ? qpart[(size_t)bh * NT + t] : 0.0;
  __syncthreads();
  for (int s = 128; s > 0; s >>= 1) { if (t < s) sh[t] += sh[t + s]; __syncthreads(); }
  if (t == 0) sqa[bh] = sh[0];
  __syncthreads();
  sh[t] = (t < NT) ? kpart[(size_t)bh * NT + t] : 0.0;
  __syncthreads();
  for (int s = 128; s > 0; s >>= 1) { if (t < s) sh[t] += sh[t + s]; __syncthreads(); }
  if (t == 0) ska[bh] = sh[0];
}

// ---------- 2) attention: LDS-P PV, 4 accumulators, n split 4 ways ----------
__global__ __launch_bounds__(256) void attn_f64(
    const uint64_t* __restrict__ qbits, const uint64_t* __restrict__ kbits,
    const int8_t* __restrict__ vq8, const double* __restrict__ sqa,
    const double* __restrict__ ska, const float* __restrict__ rel_table,
    const int* __restrict__ rel_index, int* __restrict__ attn_acc,
    const int* __restrict__ flag) {
  __shared__ uint64_t qsh[NT];
  __shared__ uint64_t ksh[NT];
  __shared__ int8_t vsh8[NT * 64];   // 12.6 KB, raw int8 (broadcast reads)
  __shared__ float rtabf[732];       // 2.9 KB f32 (cvt at use is exact)
  __shared__ int psh[4][200];        // 3.2 KB per-wave P strip

  const int f = flag[0];
  const int bh = blockIdx.x;
  const int qtr = blockIdx.y;        // 0..3
  const int n0 = qtr * 50;
  const int n1 = (qtr == 3) ? NT : n0 + 50;
  const int b = bh / HH, h = bh - b * HH;
  const int t = threadIdx.x;
  const int wv = t >> 6, lane = t & 63;

  const double s_q = sqa[bh] / (double)(NT * 64);
  const double s_k = ska[bh] / (double)(NT * 64);
  const double coef = s_q * s_k * 0.125;

  if (t < NT) {
    qsh[t] = qbits[(size_t)bh * NT + t];
    ksh[t] = kbits[(size_t)bh * NT + t];
  }
  for (int idx = t; idx < 732; idx += 256)
    rtabf[idx] = rel_table[idxRT(f, idx, h)];
  {
    const int4* vsrc = (const int4*)(vq8 + (size_t)bh * NT * 64);
    int4* vdst = (int4*)vsh8;
    for (int idx = t; idx < NT * 4; idx += 256)   // 788 int4 words
      vdst[idx] = vsrc[idx];
  }
  __syncthreads();   // the ONLY barrier

  int* aout = attn_acc + (size_t)(b * NT) * CD + h * 64;   // + n*CD + dd

  for (int n = n0 + wv; n < n1; n += 4) {
    const uint64_t qb = qsh[n];
    double lt[4];
    #pragma unroll
    for (int i = 0; i < 4; i++) {
      const int m = lane + 64 * i;
      if (m < NT) {
        const int dot = 64 - 2 * (int)__popcll(qb ^ ksh[m]);
        lt[i] = coef * (double)dot + (double)rtabf[rel_index[idxRI(f, n, m)]];
      } else {
        lt[i] = -1e300;
      }
    }
    double mx = fmax(fmax(lt[0], lt[1]), fmax(lt[2], lt[3]));
    #pragma unroll
    for (int off = 1; off < 64; off <<= 1) mx = fmax(mx, __shfl_xor(mx, off));
    double et[4];
    #pragma unroll
    for (int i = 0; i < 4; i++)
      et[i] = (lane + 64 * i < NT) ? exp(lt[i] - mx) : 0.0;
    double sl = (et[0] + et[1]) + (et[2] + et[3]);
    #pragma unroll
    for (int off = 1; off < 64; off <<= 1) sl += __shfl_xor(sl, off);
    const double sum = sl;
    // P -> LDS strip (int). Same wave writes then reads: no barrier needed.
    const double sP = 1.0 / 255.0;
    #pragma unroll
    for (int i = 0; i < 4; i++) {
      const int m = lane + 64 * i;
      if (m < NT) {
        double P = rint((et[i] / sum) / sP);
        P = fmin(fmax(P, 0.0), 255.0);
        psh[wv][m] = (int)P;
      }
    }
    // PV: 4 independent int accumulators (exact -> deterministic).
    // P read broadcast (same addr all lanes); V int8 64 consecutive bytes
    // (4 lanes/dword, conflict-free). All indices < NT*64 (in bounds).
    int a0 = 0, a1 = 0, a2 = 0, a3 = 0;
    const int* pw = psh[wv];
    for (int m = 0; m < 196; m += 4) {
      a0 += pw[m + 0] * (int)vsh8[(m + 0) * 64 + lane];
      a1 += pw[m + 1] * (int)vsh8[(m + 1) * 64 + lane];
      a2 += pw[m + 2] * (int)vsh8[(m + 2) * 64 + lane];
      a3 += pw[m + 3] * (int)vsh8[(m + 3) * 64 + lane];
    }
    a0 += pw[196] * (int)vsh8[196 * 64 + lane];
    aout[(size_t)n * CD + lane] = (a0 + a1) + (a2 + a3);
  }
}

// ---------- 3a) proj GEMM, SCALAR fallback (verbatim R17) ----------
__global__ __launch_bounds__(256, 3) void proj_g(
    const int* __restrict__ attn_acc, const float* __restrict__ w,
    const float* __restrict__ bias, float* __restrict__ out,
    const int* __restrict__ flag) {
  __shared__ float wsm[256][34];
  __shared__ double xsm[RB][32];

  if (flag[1] != 0) return;
  const int f = flag[0];
  const int t = threadIdx.x;
  const int wv = t >> 6, lane = t & 63;
  const int cBase = blockIdx.x * 256;
  const int row0 = blockIdx.y * RB;

  double acc[4][8];
  #pragma unroll
  for (int j = 0; j < 4; j++)
    #pragma unroll
    for (int i = 0; i < 8; i++) acc[j][i] = 0.0;

  if (f == 0) {
    for (int k0 = 0; k0 < CD; k0 += 32) {
      #pragma unroll
      for (int j = 0; j < 8; j++) {
        const int flat = t + 256 * j;
        const int r = flat >> 3, kq = flat & 7;
        const float4 v4 = *reinterpret_cast<const float4*>(
            w + (size_t)(cBase + r) * CD + k0 + kq * 4);
        wsm[r][kq * 4 + 0] = v4.x; wsm[r][kq * 4 + 1] = v4.y;
        wsm[r][kq * 4 + 2] = v4.z; wsm[r][kq * 4 + 3] = v4.w;
      }
      #pragma unroll
      for (int j = 0; j < 4; j++) {
        const int flat = t + 256 * j;
        const int r = flat >> 5, kk = flat & 31;
        xsm[r][kk] = (double)attn_acc[(size_t)(row0 + r) * CD + k0 + kk];
      }
      __syncthreads();
      for (int kk = 0; kk < 32; kk += 2) {
        double2 xv[8];
        #pragma unroll
        for (int i = 0; i < 8; i++)
          xv[i] = *reinterpret_cast<const double2*>(&xsm[wv * 8 + i][kk]);
        double w0[4], w1[4];
        #pragma unroll
        for (int j = 0; j < 4; j++) {
          const float2 wf = *reinterpret_cast<const float2*>(&wsm[lane + 64 * j][kk]);
          w0[j] = (double)wf.x; w1[j] = (double)wf.y;
        }
        #pragma unroll
        for (int j = 0; j < 4; j++)
          #pragma unroll
          for (int i = 0; i < 8; i++) {
            acc[j][i] += xv[i].x * w0[j];
            acc[j][i] += xv[i].y * w1[j];
          }
      }
      __syncthreads();
    }
  } else {
    for (int k = 0; k < CD; k++) {
      double w0[4];
      #pragma unroll
      for (int j = 0; j < 4; j++)
        w0[j] = (double)w[(size_t)(cBase + lane + 64 * j) + 768u * (size_t)k];
      #pragma unroll
      for (int i = 0; i < 8; i++) {
        const double xv = (double)attn_acc[(size_t)(row0 + wv * 8 + i) * CD + k];
        #pragma unroll
        for (int j = 0; j < 4; j++) acc[j][i] += xv * w0[j];
      }
    }
  }

  const double SCALE = (1.0 / 255.0) * (2.0 / 127.0);
  #pragma unroll
  for (int j = 0; j < 4; j++) {
    const int c = cBase + lane + 64 * j;
    const double bj = (double)bias[c];
    #pragma unroll
    for (int i = 0; i < 8; i++) {
      const int row = row0 + wv * 8 + i, b = row / NT, n = row - b * NT;
      out[idxX(f, b, n, c)] = (float)(acc[j][i] * SCALE + bj);
    }
  }
}

// ---------- 3b) proj GEMM via f64 MFMA (runs only if flag[1]>=1) ----------
__global__ __launch_bounds__(256) void proj_mf(
    const int* __restrict__ attn_acc, const float* __restrict__ w,
    const float* __restrict__ bias, float* __restrict__ out,
    const int* __restrict__ flag) {
  __shared__ double xsm[64][33];
  __shared__ double wsm[64][33];

  if (flag[1] == 0) return;
  const int dmap = flag[1] - 1;
  const int f = flag[0];
  const int t = threadIdx.x;
  const int wv = t >> 6, lane = t & 63;
  const int p = lane & 15, q = lane >> 4;
  const int cBase = blockIdx.x * 64;
  const int row0 = blockIdx.y * 64;

  f64x4 acc[4];
  #pragma unroll
  for (int j = 0; j < 4; j++) acc[j] = (f64x4){0.0, 0.0, 0.0, 0.0};

  for (int k0 = 0; k0 < CD; k0 += 32) {
    #pragma unroll
    for (int jj = 0; jj < 2; jj++) {
      const int idx = t + 256 * jj;
      const int r = idx >> 3, kq = idx & 7;
      const int4 v4 = *reinterpret_cast<const int4*>(
          attn_acc + (size_t)(row0 + r) * CD + k0 + kq * 4);
      xsm[r][kq * 4 + 0] = (double)v4.x; xsm[r][kq * 4 + 1] = (double)v4.y;
      xsm[r][kq * 4 + 2] = (double)v4.z; xsm[r][kq * 4 + 3] = (double)v4.w;
    }
    if (f == 0) {
      #pragma unroll
      for (int jj = 0; jj < 2; jj++) {
        const int idx = t + 256 * jj;
        const int r = idx >> 3, kq = idx & 7;
        const float4 v4 = *reinterpret_cast<const float4*>(
            w + (size_t)(cBase + r) * CD + k0 + kq * 4);
        wsm[r][kq * 4 + 0] = (double)v4.x; wsm[r][kq * 4 + 1] = (double)v4.y;
        wsm[r][kq * 4 + 2] = (double)v4.z; wsm[r][kq * 4 + 3] = (double)v4.w;
      }
    } else {
      for (int idx = t; idx < 2048; idx += 256) {
        const int r = idx >> 5, kk = idx & 31;
        wsm[r][kk] = (double)w[(size_t)(cBase + r) + 768u * (size_t)(k0 + kk)];
      }
    }
    __syncthreads();
    #pragma unroll
    for (int ks = 0; ks < 8; ks++) {
      const double a = xsm[wv * 16 + p][ks * 4 + q];
      #pragma unroll
      for (int j = 0; j < 4; j++) {
        const double bb = wsm[j * 16 + p][ks * 4 + q];
        acc[j] = __builtin_amdgcn_mfma_f64_16x16x4f64(a, bb, acc[j], 0, 0, 0);
      }
    }
    __syncthreads();
  }

  const double SCALE = (1.0 / 255.0) * (2.0 / 127.0);
  #pragma unroll
  for (int j = 0; j < 4; j++) {
    #pragma unroll
    for (int r = 0; r < 4; r++) {
      const int g = (dmap & 1) ? (q + 4 * r) : (4 * q + r);
      const int rr = (dmap & 2) ? p : g;
      const int cc = (dmap & 2) ? g : p;
      const int row = row0 + wv * 16 + rr;
      const int b = row / NT, n = row - b * NT;
      const int c = cBase + j * 16 + cc;
      out[idxX(f, b, n, c)] = (float)(acc[j][r] * SCALE + (double)bias[c]);
    }
  }
}

// ---------------- host launch ----------------
extern "C" void kernel_launch(void* const* d_in, const int* in_sizes, int n_in,
                              void* d_out, int out_size, void* d_ws, size_t ws_size,
                              hipStream_t stream) {
  (void)out_size; (void)ws_size;

  const float* x = nullptr;
  const float* qkv_w = nullptr;
  const float* proj_w = nullptr;
  const float* proj_b = nullptr;
  const float* rel_table = nullptr;
  const int* rel_index = nullptr;
  for (int i = 0; i < n_in; i++) {
    switch (in_sizes[i]) {
      case 9682944: x         = (const float*)d_in[i]; break;
      case 1769472: qkv_w     = (const float*)d_in[i]; break;
      case 589824:  proj_w    = (const float*)d_in[i]; break;
      case 768:     proj_b    = (const float*)d_in[i]; break;
      case 8784:    rel_table = (const float*)d_in[i]; break;
      case 38809:   rel_index = (const int*)d_in[i];   break;
      default: break;
    }
  }
  if (!x)         x         = (const float*)d_in[0];
  if (!qkv_w)     qkv_w     = (const float*)d_in[1];
  if (!proj_w)    proj_w    = (const float*)d_in[2];
  if (!proj_b)    proj_b    = (const float*)d_in[3];
  if (!rel_table) rel_table = (const float*)d_in[4];
  if (!rel_index) rel_index = (const int*)d_in[5];
  float* out = (float*)d_out;

  uint8_t* ws = (uint8_t*)d_ws;
  int*      flag     = (int*)(ws + 0);              //         64
  double*   sqa      = (double*)(ws + 64);          //      6,144
  double*   ska      = (double*)(ws + 6208);        //      6,144
  double*   qpart    = (double*)(ws + 12352);       //  1,210,368
  double*   kpart    = (double*)(ws + 1222720);     //  1,210,368
  uint64_t* qbits    = (uint64_t*)(ws + 2433088);   //  1,210,368
  uint64_t* kbits    = (uint64_t*)(ws + 3643456);   //  1,210,368
  int8_t*   vq8      = (int8_t*)(ws + 4853824);     //  9,682,944
  int*      attn_acc = (int*)(ws + 14536768);       // 38,731,776 -> 53,268,544

  probe_orient<<<1, 64, 0, stream>>>(rel_index, flag);
  // both qkv variants launch; exactly one does work (flag[1] guard)
  qkv_g<<<dim3(9, YB), 256, 0, stream>>>(x, qkv_w, qbits, kbits, vq8,
                                         qpart, kpart, flag);
  qkv_mf<<<dim3(36, 197), 256, 0, stream>>>(x, qkv_w, qbits, kbits, vq8,
                                            qpart, kpart, flag);
  reduce_s<<<NBH, 256, 0, stream>>>(qpart, kpart, sqa, ska);
  attn_f64<<<dim3(NBH, 4), 256, 0, stream>>>(qbits, kbits, vq8, sqa, ska,
                                             rel_table, rel_index, attn_acc, flag);
  proj_g<<<dim3(3, YB), 256, 0, stream>>>(attn_acc, proj_w, proj_b, out, flag);
  proj_mf<<<dim3(12, 197), 256, 0, stream>>>(attn_acc, proj_w, proj_b, out, flag);
}

// Round 16
// 1460.980 us; speedup vs baseline: 1.4195x; 1.0115x over previous
//
#include <hip/hip_runtime.h>
#include <stdint.h>

// BinaryAttention on MI355X (gfx950).  B=64, N=197, C=768, H=12, d=64.
//
// ROUND 27 — REGISTER DOUBLE-BUFFERED STAGING (qkv_mf / proj_mf, f==0 path).
// R26: 1478 us, attn fixed (LDS-P PV). Profile: qkv_mf 900 us = 61% of total,
// MfmaUtil 68% vs 567 us f64-matrix floor. Stall: staging (global load ->
// cvt -> ds_write) exposed between the two per-K-tile barriers; only 4
// blocks/CU to hide ~500cy global latency. Fix (G15/T14): issue tile k+1's
// float4/int4 loads into REGISTERS right after the write barrier, BEFORE the
// MFMA loop (loads fly under 2048 cy of MFMA); next write phase starts from
// registers. Zero numeric change -> absmax bit-identical. Same for proj_mf.
// attn (R26), probe, fallbacks, reduce_s: verbatim.

#define NT 197
#define HH 12
#define CD 768
#define NB 64
#define MROWS (NB * NT)   // 12608
#define NBH (NB * HH)     // 768
#define RB 32             // rows per block (scalar GEMM)
#define YB (MROWS / RB)   // 394

typedef double f64x4 __attribute__((ext_vector_type(4)));

// ---- flag-selected flat indexers (flag: 0 = C-order, 1 = F-order) ----
__device__ __forceinline__ size_t idxX(int f, int b, int n, int c) {
  return f ? ((size_t)b + 64u * (size_t)n + 12608u * (size_t)c)
           : ((size_t)(b * NT + n) * CD + c);
}
__device__ __forceinline__ size_t idxRT(int f, int i, int h) {  // rel_table [732,12]
  return f ? ((size_t)i + 732u * (size_t)h) : ((size_t)i * HH + h);
}
__device__ __forceinline__ size_t idxRI(int f, int n, int m) {  // rel_index [197,197]
  return f ? ((size_t)n + 197u * (size_t)m) : ((size_t)n * NT + m);
}

// ---- orientation probe + MFMA D-layout discovery ----
__global__ __launch_bounds__(64) void probe_orient(const int* __restrict__ ri,
                                                   int* __restrict__ flag) {
  const int lane = threadIdx.x;   // 0..63
  const int p = lane & 15, q = lane >> 4;
  const double av = (double)(p * 4 + q + 1);          // A[m=p][k=q]
  const double bv = (double)((q + 1) * 100 + p + 1);  // B[k=q][n=p]
  f64x4 c0 = {0.0, 0.0, 0.0, 0.0};
  f64x4 d = __builtin_amdgcn_mfma_f64_16x16x4f64(av, bv, c0, 0, 0, 0);
  int best = 0;
  #pragma unroll
  for (int cand = 0; cand < 4; cand++) {
    bool ok = true;
    #pragma unroll
    for (int r = 0; r < 4; r++) {
      const int g = (cand & 1) ? (q + 4 * r) : (4 * q + r);
      const int m = (cand & 2) ? p : g;
      const int n = (cand & 2) ? g : p;
      double ref = 0.0;
      #pragma unroll
      for (int k = 0; k < 4; k++)
        ref += (double)((m * 4 + k + 1) * ((k + 1) * 100 + n + 1));
      ok = ok && (d[r] == ref);
    }
    if (__ballot(ok) == 0xFFFFFFFFFFFFFFFFull && best == 0) best = cand + 1;
  }
  if (lane == 0) {
    const int aa = ri[1], bb = ri[197];
    flag[0] = (aa == 730 && bb == 729) ? 1 : 0;
    flag[1] = best;   // 0 = no candidate matched -> scalar fallback
  }
}

// ---------- 1a) qkv GEMM, SCALAR fallback (verbatim R17, verified) ----------
__global__ __launch_bounds__(256, 3) void qkv_g(
    const float* __restrict__ x, const float* __restrict__ w,
    uint64_t* __restrict__ qbits, uint64_t* __restrict__ kbits,
    int8_t* __restrict__ vq8, double* __restrict__ qpart,
    double* __restrict__ kpart, const int* __restrict__ flag) {
  __shared__ float wsm[256][34];
  __shared__ double xsm[RB][32];

  if (flag[1] != 0) return;
  const int f = flag[0];
  const int t = threadIdx.x;
  const int wv = t >> 6, lane = t & 63;
  const int cBase = blockIdx.x * 256;
  const int row0 = blockIdx.y * RB;

  double acc[4][8];
  #pragma unroll
  for (int j = 0; j < 4; j++)
    #pragma unroll
    for (int i = 0; i < 8; i++) acc[j][i] = 0.0;

  if (f == 0) {
    for (int k0 = 0; k0 < CD; k0 += 32) {
      #pragma unroll
      for (int j = 0; j < 8; j++) {
        const int flat = t + 256 * j;
        const int r = flat >> 3, kq = flat & 7;
        const float4 v4 = *reinterpret_cast<const float4*>(
            w + (size_t)(cBase + r) * CD + k0 + kq * 4);
        wsm[r][kq * 4 + 0] = v4.x; wsm[r][kq * 4 + 1] = v4.y;
        wsm[r][kq * 4 + 2] = v4.z; wsm[r][kq * 4 + 3] = v4.w;
      }
      #pragma unroll
      for (int j = 0; j < 4; j++) {
        const int flat = t + 256 * j;
        const int r = flat >> 5, kk = flat & 31;
        xsm[r][kk] = (double)x[(size_t)(row0 + r) * CD + k0 + kk];
      }
      __syncthreads();
      for (int kk = 0; kk < 32; kk += 2) {
        double2 xv[8];
        #pragma unroll
        for (int i = 0; i < 8; i++)
          xv[i] = *reinterpret_cast<const double2*>(&xsm[wv * 8 + i][kk]);
        double w0[4], w1[4];
        #pragma unroll
        for (int j = 0; j < 4; j++) {
          const float2 wf = *reinterpret_cast<const float2*>(&wsm[lane + 64 * j][kk]);
          w0[j] = (double)wf.x; w1[j] = (double)wf.y;
        }
        #pragma unroll
        for (int j = 0; j < 4; j++)
          #pragma unroll
          for (int i = 0; i < 8; i++) {
            acc[j][i] += xv[i].x * w0[j];
            acc[j][i] += xv[i].y * w1[j];
          }
      }
      __syncthreads();
    }
  } else {
    for (int k = 0; k < CD; k++) {
      double w0[4];
      #pragma unroll
      for (int j = 0; j < 4; j++)
        w0[j] = (double)w[(size_t)(cBase + lane + 64 * j) + 2304u * (size_t)k];
      #pragma unroll
      for (int i = 0; i < 8; i++) {
        const int row = row0 + wv * 8 + i, b = row / NT, n = row - b * NT;
        const double xv = (double)x[(size_t)b + 64u * (size_t)n + 12608u * (size_t)k];
        #pragma unroll
        for (int j = 0; j < 4; j++) acc[j][i] += xv * w0[j];
      }
    }
  }

  const int kind = cBase / CD;
  const int hBase = (cBase - kind * CD) >> 6;
  #pragma unroll
  for (int j = 0; j < 4; j++) {
    const int h = hBase + j;
    #pragma unroll
    for (int i = 0; i < 8; i++) {
      const int row = row0 + wv * 8 + i, b = row / NT, n = row - b * NT;
      const int bh = b * HH + h;
      const double a = acc[j][i];
      if (kind == 2) {
        const double sV = 2.0 / 127.0;
        double vc = fmin(fmax(a, -2.0), 2.0);
        double vq = rint(vc / sV);
        vq = fmin(fmax(vq, -127.0), 127.0);
        vq8[(size_t)(bh * NT + n) * 64 + lane] = (int8_t)(int)vq;
      } else {
        const uint64_t msk = __ballot(a < 0.0);
        double s = fabs(a);
        #pragma unroll
        for (int off = 1; off < 64; off <<= 1) s += __shfl_xor(s, off);
        if (lane == 0) {
          if (kind == 0) { qbits[(size_t)bh * NT + n] = msk; qpart[(size_t)bh * NT + n] = s; }
          else           { kbits[(size_t)bh * NT + n] = msk; kpart[(size_t)bh * NT + n] = s; }
        }
      }
    }
  }
}

// ---------- 1b) qkv GEMM via f64 MFMA, register double-buffered ----------
union SmemQ {
  struct { double xs[64][33]; double ws[64][33]; } t;   // K-loop tiles
  double d[64][65];                                     // D round-trip
};
__global__ __launch_bounds__(256) void qkv_mf(
    const float* __restrict__ x, const float* __restrict__ w,
    uint64_t* __restrict__ qbits, uint64_t* __restrict__ kbits,
    int8_t* __restrict__ vq8, double* __restrict__ qpart,
    double* __restrict__ kpart, const int* __restrict__ flag) {
  __shared__ SmemQ sm;

  if (flag[1] == 0) return;
  const int dmap = flag[1] - 1;
  const int f = flag[0];
  const int t = threadIdx.x;
  const int wv = t >> 6, lane = t & 63;
  const int p = lane & 15, q = lane >> 4;
  const int cBase = blockIdx.x * 64;
  const int row0 = blockIdx.y * 64;
  const int kind = cBase / CD;
  const int h = (cBase - kind * CD) >> 6;

  f64x4 acc[4];
  #pragma unroll
  for (int j = 0; j < 4; j++) acc[j] = (f64x4){0.0, 0.0, 0.0, 0.0};

  if (f == 0) {
    // register double-buffer: loads for tile k+1 issued before MFMA on tile k
    const int r = t >> 3, kq = t & 7;           // this thread's stage slot
    const int r2 = (t + 256) >> 3, kq2 = (t + 256) & 7;
    float4 px0, px1, pw0, pw1;
    px0 = *reinterpret_cast<const float4*>(x + (size_t)(row0 + r) * CD + kq * 4);
    px1 = *reinterpret_cast<const float4*>(x + (size_t)(row0 + r2) * CD + kq2 * 4);
    pw0 = *reinterpret_cast<const float4*>(w + (size_t)(cBase + r) * CD + kq * 4);
    pw1 = *reinterpret_cast<const float4*>(w + (size_t)(cBase + r2) * CD + kq2 * 4);
    for (int k0 = 0; k0 < CD; k0 += 32) {
      // write current regs -> LDS (cvt f64)
      sm.t.xs[r][kq * 4 + 0] = (double)px0.x; sm.t.xs[r][kq * 4 + 1] = (double)px0.y;
      sm.t.xs[r][kq * 4 + 2] = (double)px0.z; sm.t.xs[r][kq * 4 + 3] = (double)px0.w;
      sm.t.xs[r2][kq2 * 4 + 0] = (double)px1.x; sm.t.xs[r2][kq2 * 4 + 1] = (double)px1.y;
      sm.t.xs[r2][kq2 * 4 + 2] = (double)px1.z; sm.t.xs[r2][kq2 * 4 + 3] = (double)px1.w;
      sm.t.ws[r][kq * 4 + 0] = (double)pw0.x; sm.t.ws[r][kq * 4 + 1] = (double)pw0.y;
      sm.t.ws[r][kq * 4 + 2] = (double)pw0.z; sm.t.ws[r][kq * 4 + 3] = (double)pw0.w;
      sm.t.ws[r2][kq2 * 4 + 0] = (double)pw1.x; sm.t.ws[r2][kq2 * 4 + 1] = (double)pw1.y;
      sm.t.ws[r2][kq2 * 4 + 2] = (double)pw1.z; sm.t.ws[r2][kq2 * 4 + 3] = (double)pw1.w;
      __syncthreads();
      // prefetch next tile (flies under the MFMA loop)
      if (k0 + 32 < CD) {
        const int kn = k0 + 32;
        px0 = *reinterpret_cast<const float4*>(x + (size_t)(row0 + r) * CD + kn + kq * 4);
        px1 = *reinterpret_cast<const float4*>(x + (size_t)(row0 + r2) * CD + kn + kq2 * 4);
        pw0 = *reinterpret_cast<const float4*>(w + (size_t)(cBase + r) * CD + kn + kq * 4);
        pw1 = *reinterpret_cast<const float4*>(w + (size_t)(cBase + r2) * CD + kn + kq2 * 4);
      }
      #pragma unroll
      for (int ks = 0; ks < 8; ks++) {
        const double a = sm.t.xs[wv * 16 + p][ks * 4 + q];
        #pragma unroll
        for (int j = 0; j < 4; j++) {
          const double bb = sm.t.ws[j * 16 + p][ks * 4 + q];
          acc[j] = __builtin_amdgcn_mfma_f64_16x16x4f64(a, bb, acc[j], 0, 0, 0);
        }
      }
      __syncthreads();
    }
  } else {
    for (int k0 = 0; k0 < CD; k0 += 32) {
      for (int idx = t; idx < 2048; idx += 256) {
        const int r = idx >> 5, kk = idx & 31;
        const int row = row0 + r, b = row / NT, n = row - b * NT;
        sm.t.xs[r][kk] = (double)x[(size_t)b + 64u * (size_t)n + 12608u * (size_t)(k0 + kk)];
        sm.t.ws[r][kk] = (double)w[(size_t)(cBase + r) + 2304u * (size_t)(k0 + kk)];
      }
      __syncthreads();
      #pragma unroll
      for (int ks = 0; ks < 8; ks++) {
        const double a = sm.t.xs[wv * 16 + p][ks * 4 + q];
        #pragma unroll
        for (int j = 0; j < 4; j++) {
          const double bb = sm.t.ws[j * 16 + p][ks * 4 + q];
          acc[j] = __builtin_amdgcn_mfma_f64_16x16x4f64(a, bb, acc[j], 0, 0, 0);
        }
      }
      __syncthreads();
    }
  }

  // D -> LDS via the DISCOVERED map, then R17-structure epilogue.
  #pragma unroll
  for (int j = 0; j < 4; j++)
    #pragma unroll
    for (int r = 0; r < 4; r++) {
      const int g = (dmap & 1) ? (q + 4 * r) : (4 * q + r);
      const int rr = (dmap & 2) ? p : g;
      const int cc = (dmap & 2) ? g : p;
      sm.d[wv * 16 + rr][j * 16 + cc] = acc[j][r];
    }
  __syncthreads();

  if (kind == 2) {
    const double sV = 2.0 / 127.0;
    for (int i = 0; i < 16; i++) {
      const int row = row0 + wv * 16 + i;
      const int b = row / NT, n = row - b * NT, bh = b * HH + h;
      const double a = sm.d[wv * 16 + i][lane];
      double vc = fmin(fmax(a, -2.0), 2.0);
      double vq = rint(vc / sV);
      vq = fmin(fmax(vq, -127.0), 127.0);
      vq8[(size_t)(bh * NT + n) * 64 + lane] = (int8_t)(int)vq;
    }
  } else {
    for (int i = 0; i < 16; i++) {
      const int row = row0 + wv * 16 + i;
      const int b = row / NT, n = row - b * NT, bh = b * HH + h;
      const double a = sm.d[wv * 16 + i][lane];
      const uint64_t msk = __ballot(a < 0.0);
      double s = fabs(a);
      #pragma unroll
      for (int off = 1; off < 64; off <<= 1) s += __shfl_xor(s, off);
      if (lane == 0) {
        if (kind == 0) { qbits[(size_t)bh * NT + n] = msk; qpart[(size_t)bh * NT + n] = s; }
        else           { kbits[(size_t)bh * NT + n] = msk; kpart[(size_t)bh * NT + n] = s; }
      }
    }
  }
}

// ---------- 1c) deterministic fixed-order reduction of row partials ----------
__global__ __launch_bounds__(256) void reduce_s(
    const double* __restrict__ qpart, const double* __restrict__ kpart,
    double* __restrict__ sqa, double* __restrict__ ska) {
  __shared__ double sh[256];
  const int bh = blockIdx.x, t = threadIdx.x;
  sh[t] = (t < NT) ? qpart[(size_t)bh * NT + t] : 0.0;
  __syncthreads();
  for (int s = 128; s > 0; s >>= 1) { if (t < s) sh[t] += sh[t + s]; __syncthreads(); }
  if (t == 0) sqa[bh] = sh[0];
  __syncthreads();
  sh[t] = (t < NT) ? kpart[(size_t)bh * NT + t] : 0.0;
  __syncthreads();
  for (int s = 128; s > 0; s >>= 1) { if (t < s) sh[t] += sh[t + s]; __syncthreads(); }
  if (t == 0) ska[bh] = sh[0];
}

// ---------- 2) attention: LDS-P PV, 4 accumulators, n split 4 ways (R26) ----
__global__ __launch_bounds__(256) void attn_f64(
    const uint64_t* __restrict__ qbits, const uint64_t* __restrict__ kbits,
    const int8_t* __restrict__ vq8, const double* __restrict__ sqa,
    const double* __restrict__ ska, const float* __restrict__ rel_table,
    const int* __restrict__ rel_index, int* __restrict__ attn_acc,
    const int* __restrict__ flag) {
  __shared__ uint64_t qsh[NT];
  __shared__ uint64_t ksh[NT];
  __shared__ int8_t vsh8[NT * 64];   // 12.6 KB, raw int8 (broadcast reads)
  __shared__ float rtabf[732];       // 2.9 KB f32 (cvt at use is exact)
  __shared__ int psh[4][200];        // 3.2 KB per-wave P strip

  const int f = flag[0];
  const int bh = blockIdx.x;
  const int qtr = blockIdx.y;        // 0..3
  const int n0 = qtr * 50;
  const int n1 = (qtr == 3) ? NT : n0 + 50;
  const int b = bh / HH, h = bh - b * HH;
  const int t = threadIdx.x;
  const int wv = t >> 6, lane = t & 63;

  const double s_q = sqa[bh] / (double)(NT * 64);
  const double s_k = ska[bh] / (double)(NT * 64);
  const double coef = s_q * s_k * 0.125;

  if (t < NT) {
    qsh[t] = qbits[(size_t)bh * NT + t];
    ksh[t] = kbits[(size_t)bh * NT + t];
  }
  for (int idx = t; idx < 732; idx += 256)
    rtabf[idx] = rel_table[idxRT(f, idx, h)];
  {
    const int4* vsrc = (const int4*)(vq8 + (size_t)bh * NT * 64);
    int4* vdst = (int4*)vsh8;
    for (int idx = t; idx < NT * 4; idx += 256)   // 788 int4 words
      vdst[idx] = vsrc[idx];
  }
  __syncthreads();   // the ONLY barrier

  int* aout = attn_acc + (size_t)(b * NT) * CD + h * 64;   // + n*CD + dd

  for (int n = n0 + wv; n < n1; n += 4) {
    const uint64_t qb = qsh[n];
    double lt[4];
    #pragma unroll
    for (int i = 0; i < 4; i++) {
      const int m = lane + 64 * i;
      if (m < NT) {
        const int dot = 64 - 2 * (int)__popcll(qb ^ ksh[m]);
        lt[i] = coef * (double)dot + (double)rtabf[rel_index[idxRI(f, n, m)]];
      } else {
        lt[i] = -1e300;
      }
    }
    double mx = fmax(fmax(lt[0], lt[1]), fmax(lt[2], lt[3]));
    #pragma unroll
    for (int off = 1; off < 64; off <<= 1) mx = fmax(mx, __shfl_xor(mx, off));
    double et[4];
    #pragma unroll
    for (int i = 0; i < 4; i++)
      et[i] = (lane + 64 * i < NT) ? exp(lt[i] - mx) : 0.0;
    double sl = (et[0] + et[1]) + (et[2] + et[3]);
    #pragma unroll
    for (int off = 1; off < 64; off <<= 1) sl += __shfl_xor(sl, off);
    const double sum = sl;
    // P -> LDS strip (int). Same wave writes then reads: no barrier needed.
    const double sP = 1.0 / 255.0;
    #pragma unroll
    for (int i = 0; i < 4; i++) {
      const int m = lane + 64 * i;
      if (m < NT) {
        double P = rint((et[i] / sum) / sP);
        P = fmin(fmax(P, 0.0), 255.0);
        psh[wv][m] = (int)P;
      }
    }
    // PV: 4 independent int accumulators (exact -> deterministic).
    int a0 = 0, a1 = 0, a2 = 0, a3 = 0;
    const int* pw = psh[wv];
    for (int m = 0; m < 196; m += 4) {
      a0 += pw[m + 0] * (int)vsh8[(m + 0) * 64 + lane];
      a1 += pw[m + 1] * (int)vsh8[(m + 1) * 64 + lane];
      a2 += pw[m + 2] * (int)vsh8[(m + 2) * 64 + lane];
      a3 += pw[m + 3] * (int)vsh8[(m + 3) * 64 + lane];
    }
    a0 += pw[196] * (int)vsh8[196 * 64 + lane];
    aout[(size_t)n * CD + lane] = (a0 + a1) + (a2 + a3);
  }
}

// ---------- 3a) proj GEMM, SCALAR fallback (verbatim R17) ----------
__global__ __launch_bounds__(256, 3) void proj_g(
    const int* __restrict__ attn_acc, const float* __restrict__ w,
    const float* __restrict__ bias, float* __restrict__ out,
    const int* __restrict__ flag) {
  __shared__ float wsm[256][34];
  __shared__ double xsm[RB][32];

  if (flag[1] != 0) return;
  const int f = flag[0];
  const int t = threadIdx.x;
  const int wv = t >> 6, lane = t & 63;
  const int cBase = blockIdx.x * 256;
  const int row0 = blockIdx.y * RB;

  double acc[4][8];
  #pragma unroll
  for (int j = 0; j < 4; j++)
    #pragma unroll
    for (int i = 0; i < 8; i++) acc[j][i] = 0.0;

  if (f == 0) {
    for (int k0 = 0; k0 < CD; k0 += 32) {
      #pragma unroll
      for (int j = 0; j < 8; j++) {
        const int flat = t + 256 * j;
        const int r = flat >> 3, kq = flat & 7;
        const float4 v4 = *reinterpret_cast<const float4*>(
            w + (size_t)(cBase + r) * CD + k0 + kq * 4);
        wsm[r][kq * 4 + 0] = v4.x; wsm[r][kq * 4 + 1] = v4.y;
        wsm[r][kq * 4 + 2] = v4.z; wsm[r][kq * 4 + 3] = v4.w;
      }
      #pragma unroll
      for (int j = 0; j < 4; j++) {
        const int flat = t + 256 * j;
        const int r = flat >> 5, kk = flat & 31;
        xsm[r][kk] = (double)attn_acc[(size_t)(row0 + r) * CD + k0 + kk];
      }
      __syncthreads();
      for (int kk = 0; kk < 32; kk += 2) {
        double2 xv[8];
        #pragma unroll
        for (int i = 0; i < 8; i++)
          xv[i] = *reinterpret_cast<const double2*>(&xsm[wv * 8 + i][kk]);
        double w0[4], w1[4];
        #pragma unroll
        for (int j = 0; j < 4; j++) {
          const float2 wf = *reinterpret_cast<const float2*>(&wsm[lane + 64 * j][kk]);
          w0[j] = (double)wf.x; w1[j] = (double)wf.y;
        }
        #pragma unroll
        for (int j = 0; j < 4; j++)
          #pragma unroll
          for (int i = 0; i < 8; i++) {
            acc[j][i] += xv[i].x * w0[j];
            acc[j][i] += xv[i].y * w1[j];
          }
      }
      __syncthreads();
    }
  } else {
    for (int k = 0; k < CD; k++) {
      double w0[4];
      #pragma unroll
      for (int j = 0; j < 4; j++)
        w0[j] = (double)w[(size_t)(cBase + lane + 64 * j) + 768u * (size_t)k];
      #pragma unroll
      for (int i = 0; i < 8; i++) {
        const double xv = (double)attn_acc[(size_t)(row0 + wv * 8 + i) * CD + k];
        #pragma unroll
        for (int j = 0; j < 4; j++) acc[j][i] += xv * w0[j];
      }
    }
  }

  const double SCALE = (1.0 / 255.0) * (2.0 / 127.0);
  #pragma unroll
  for (int j = 0; j < 4; j++) {
    const int c = cBase + lane + 64 * j;
    const double bj = (double)bias[c];
    #pragma unroll
    for (int i = 0; i < 8; i++) {
      const int row = row0 + wv * 8 + i, b = row / NT, n = row - b * NT;
      out[idxX(f, b, n, c)] = (float)(acc[j][i] * SCALE + bj);
    }
  }
}

// ---------- 3b) proj GEMM via f64 MFMA, register double-buffered ----------
__global__ __launch_bounds__(256) void proj_mf(
    const int* __restrict__ attn_acc, const float* __restrict__ w,
    const float* __restrict__ bias, float* __restrict__ out,
    const int* __restrict__ flag) {
  __shared__ double xsm[64][33];
  __shared__ double wsm[64][33];

  if (flag[1] == 0) return;
  const int dmap = flag[1] - 1;
  const int f = flag[0];
  const int t = threadIdx.x;
  const int wv = t >> 6, lane = t & 63;
  const int p = lane & 15, q = lane >> 4;
  const int cBase = blockIdx.x * 64;
  const int row0 = blockIdx.y * 64;

  f64x4 acc[4];
  #pragma unroll
  for (int j = 0; j < 4; j++) acc[j] = (f64x4){0.0, 0.0, 0.0, 0.0};

  if (f == 0) {
    const int r = t >> 3, kq = t & 7;
    const int r2 = (t + 256) >> 3, kq2 = (t + 256) & 7;
    int4 ix0, ix1;
    float4 fw0, fw1;
    ix0 = *reinterpret_cast<const int4*>(attn_acc + (size_t)(row0 + r) * CD + kq * 4);
    ix1 = *reinterpret_cast<const int4*>(attn_acc + (size_t)(row0 + r2) * CD + kq2 * 4);
    fw0 = *reinterpret_cast<const float4*>(w + (size_t)(cBase + r) * CD + kq * 4);
    fw1 = *reinterpret_cast<const float4*>(w + (size_t)(cBase + r2) * CD + kq2 * 4);
    for (int k0 = 0; k0 < CD; k0 += 32) {
      xsm[r][kq * 4 + 0] = (double)ix0.x; xsm[r][kq * 4 + 1] = (double)ix0.y;
      xsm[r][kq * 4 + 2] = (double)ix0.z; xsm[r][kq * 4 + 3] = (double)ix0.w;
      xsm[r2][kq2 * 4 + 0] = (double)ix1.x; xsm[r2][kq2 * 4 + 1] = (double)ix1.y;
      xsm[r2][kq2 * 4 + 2] = (double)ix1.z; xsm[r2][kq2 * 4 + 3] = (double)ix1.w;
      wsm[r][kq * 4 + 0] = (double)fw0.x; wsm[r][kq * 4 + 1] = (double)fw0.y;
      wsm[r][kq * 4 + 2] = (double)fw0.z; wsm[r][kq * 4 + 3] = (double)fw0.w;
      wsm[r2][kq2 * 4 + 0] = (double)fw1.x; wsm[r2][kq2 * 4 + 1] = (double)fw1.y;
      wsm[r2][kq2 * 4 + 2] = (double)fw1.z; wsm[r2][kq2 * 4 + 3] = (double)fw1.w;
      __syncthreads();
      if (k0 + 32 < CD) {
        const int kn = k0 + 32;
        ix0 = *reinterpret_cast<const int4*>(attn_acc + (size_t)(row0 + r) * CD + kn + kq * 4);
        ix1 = *reinterpret_cast<const int4*>(attn_acc + (size_t)(row0 + r2) * CD + kn + kq2 * 4);
        fw0 = *reinterpret_cast<const float4*>(w + (size_t)(cBase + r) * CD + kn + kq * 4);
        fw1 = *reinterpret_cast<const float4*>(w + (size_t)(cBase + r2) * CD + kn + kq2 * 4);
      }
      #pragma unroll
      for (int ks = 0; ks < 8; ks++) {
        const double a = xsm[wv * 16 + p][ks * 4 + q];
        #pragma unroll
        for (int j = 0; j < 4; j++) {
          const double bb = wsm[j * 16 + p][ks * 4 + q];
          acc[j] = __builtin_amdgcn_mfma_f64_16x16x4f64(a, bb, acc[j], 0, 0, 0);
        }
      }
      __syncthreads();
    }
  } else {
    for (int k0 = 0; k0 < CD; k0 += 32) {
      #pragma unroll
      for (int jj = 0; jj < 2; jj++) {
        const int idx = t + 256 * jj;
        const int r = idx >> 3, kq = idx & 7;
        const int4 v4 = *reinterpret_cast<const int4*>(
            attn_acc + (size_t)(row0 + r) * CD + k0 + kq * 4);
        xsm[r][kq * 4 + 0] = (double)v4.x; xsm[r][kq * 4 + 1] = (double)v4.y;
        xsm[r][kq * 4 + 2] = (double)v4.z; xsm[r][kq * 4 + 3] = (double)v4.w;
      }
      for (int idx = t; idx < 2048; idx += 256) {
        const int r = idx >> 5, kk = idx & 31;
        wsm[r][kk] = (double)w[(size_t)(cBase + r) + 768u * (size_t)(k0 + kk)];
      }
      __syncthreads();
      #pragma unroll
      for (int ks = 0; ks < 8; ks++) {
        const double a = xsm[wv * 16 + p][ks * 4 + q];
        #pragma unroll
        for (int j = 0; j < 4; j++) {
          const double bb = wsm[j * 16 + p][ks * 4 + q];
          acc[j] = __builtin_amdgcn_mfma_f64_16x16x4f64(a, bb, acc[j], 0, 0, 0);
        }
      }
      __syncthreads();
    }
  }

  const double SCALE = (1.0 / 255.0) * (2.0 / 127.0);
  #pragma unroll
  for (int j = 0; j < 4; j++) {
    #pragma unroll
    for (int r = 0; r < 4; r++) {
      const int g = (dmap & 1) ? (q + 4 * r) : (4 * q + r);
      const int rr = (dmap & 2) ? p : g;
      const int cc = (dmap & 2) ? g : p;
      const int row = row0 + wv * 16 + rr;
      const int b = row / NT, n = row - b * NT;
      const int c = cBase + j * 16 + cc;
      out[idxX(f, b, n, c)] = (float)(acc[j][r] * SCALE + (double)bias[c]);
    }
  }
}

// ---------------- host launch ----------------
extern "C" void kernel_launch(void* const* d_in, const int* in_sizes, int n_in,
                              void* d_out, int out_size, void* d_ws, size_t ws_size,
                              hipStream_t stream) {
  (void)out_size; (void)ws_size;

  const float* x = nullptr;
  const float* qkv_w = nullptr;
  const float* proj_w = nullptr;
  const float* proj_b = nullptr;
  const float* rel_table = nullptr;
  const int* rel_index = nullptr;
  for (int i = 0; i < n_in; i++) {
    switch (in_sizes[i]) {
      case 9682944: x         = (const float*)d_in[i]; break;
      case 1769472: qkv_w     = (const float*)d_in[i]; break;
      case 589824:  proj_w    = (const float*)d_in[i]; break;
      case 768:     proj_b    = (const float*)d_in[i]; break;
      case 8784:    rel_table = (const float*)d_in[i]; break;
      case 38809:   rel_index = (const int*)d_in[i];   break;
      default: break;
    }
  }
  if (!x)         x         = (const float*)d_in[0];
  if (!qkv_w)     qkv_w     = (const float*)d_in[1];
  if (!proj_w)    proj_w    = (const float*)d_in[2];
  if (!proj_b)    proj_b    = (const float*)d_in[3];
  if (!rel_table) rel_table = (const float*)d_in[4];
  if (!rel_index) rel_index = (const int*)d_in[5];
  float* out = (float*)d_out;

  uint8_t* ws = (uint8_t*)d_ws;
  int*      flag     = (int*)(ws + 0);              //         64
  double*   sqa      = (double*)(ws + 64);          //      6,144
  double*   ska      = (double*)(ws + 6208);        //      6,144
  double*   qpart    = (double*)(ws + 12352);       //  1,210,368
  double*   kpart    = (double*)(ws + 1222720);     //  1,210,368
  uint64_t* qbits    = (uint64_t*)(ws + 2433088);   //  1,210,368
  uint64_t* kbits    = (uint64_t*)(ws + 3643456);   //  1,210,368
  int8_t*   vq8      = (int8_t*)(ws + 4853824);     //  9,682,944
  int*      attn_acc = (int*)(ws + 14536768);       // 38,731,776 -> 53,268,544

  probe_orient<<<1, 64, 0, stream>>>(rel_index, flag);
  // both qkv variants launch; exactly one does work (flag[1] guard)
  qkv_g<<<dim3(9, YB), 256, 0, stream>>>(x, qkv_w, qbits, kbits, vq8,
                                         qpart, kpart, flag);
  qkv_mf<<<dim3(36, 197), 256, 0, stream>>>(x, qkv_w, qbits, kbits, vq8,
                                            qpart, kpart, flag);
  reduce_s<<<NBH, 256, 0, stream>>>(qpart, kpart, sqa, ska);
  attn_f64<<<dim3(NBH, 4), 256, 0, stream>>>(qbits, kbits, vq8, sqa, ska,
                                             rel_table, rel_index, attn_acc, flag);
  proj_g<<<dim3(3, YB), 256, 0, stream>>>(attn_acc, proj_w, proj_b, out, flag);
  proj_mf<<<dim3(12, 197), 256, 0, stream>>>(attn_acc, proj_w, proj_b, out, flag);
}